// Round 6
// baseline (200.375 us; speedup 1.0000x reference)
//
#include <hip/hip_runtime.h>

// RGCNDirectional: out = sum_r (A[r] @ (X @ W[r]^T)) / (rowsum(A[r]) + eps)
// X:[4096,128] f32, A:[8,4096,4096] f32 (512MB -> HBM-bound), W:[8,128,128] f32.
// Round 6: DRAM-contiguity restructure. BK=256, 32-row blocks: every A load
// instruction is 1KB contiguous within ONE row (the 6.3TB/s copy pattern),
// vs R1-R5's 16-row x 64B scatter (DRAM activate-bound ~3.5TB/s). A staged
// reg->cvt->bf16 LDS (convert once); waves split the o-dim; H frags direct
// from L2-resident Ht[r] (issued before A so vmcnt waits never drain A).

#define N_NODES 4096
#define DIM     128
#define NREL    8
#define EPS_F   1e-12f
#define RM      32
#define BK      256
#define NKT     (N_NODES / BK)   // 16

typedef __attribute__((ext_vector_type(4))) float f32x4;
typedef __attribute__((ext_vector_type(8))) short bf16x8;
typedef __attribute__((ext_vector_type(4))) short s16x4;

__device__ __forceinline__ unsigned short f2bf(float f) {
  unsigned u = __float_as_uint(f);
  return (unsigned short)((u + 0x7fffu + ((u >> 16) & 1u)) >> 16);   // RNE
}

__device__ __forceinline__ bf16x8 cvt8(const float* p) {
  f32x4 lo = *reinterpret_cast<const f32x4*>(p);
  f32x4 hi = *reinterpret_cast<const f32x4*>(p + 4);
  bf16x8 o;
#pragma unroll
  for (int j = 0; j < 4; ++j) { o[j] = (short)f2bf(lo[j]); o[j + 4] = (short)f2bf(hi[j]); }
  return o;
}

// ---------------------------------------------------------------------------
// Kernel 1: Ht[r][o][n] = bf16( sum_d X[n][d] * W[r][o][d] ), plain o-major.
// ---------------------------------------------------------------------------
__global__ __launch_bounds__(256) void h_kernel(const float* __restrict__ X,
                                                const float* __restrict__ W,
                                                short* __restrict__ Ht) {
  const int r  = blockIdx.x >> 5;          // 32 n-tiles of 128
  const int n0 = (blockIdx.x & 31) * 128;
  const int lane = threadIdx.x & 63;
  const int wid  = threadIdx.x >> 6;
  const int wm = wid >> 1, wn = wid & 1;   // 2x2 wave grid, 64x64 per wave
  const int l15 = lane & 15, l4 = lane >> 4;

  const float* Wr = W + (size_t)r * DIM * DIM;
  f32x4 acc[4][4] = {};

#pragma unroll
  for (int ks = 0; ks < 4; ++ks) {         // K = 128 = 4 * 32
    const int k = ks * 32 + l4 * 8;
    bf16x8 a[4], b[4];
#pragma unroll
    for (int mi = 0; mi < 4; ++mi)
      a[mi] = cvt8(Wr + (size_t)(wm * 64 + mi * 16 + l15) * DIM + k);
#pragma unroll
    for (int ni = 0; ni < 4; ++ni)
      b[ni] = cvt8(X + (size_t)(n0 + wn * 64 + ni * 16 + l15) * DIM + k);
#pragma unroll
    for (int mi = 0; mi < 4; ++mi)
#pragma unroll
      for (int ni = 0; ni < 4; ++ni)
        acc[mi][ni] = __builtin_amdgcn_mfma_f32_16x16x32_bf16(a[mi], b[ni], acc[mi][ni], 0, 0, 0);
  }

#pragma unroll
  for (int mi = 0; mi < 4; ++mi)
#pragma unroll
    for (int ni = 0; ni < 4; ++ni)
#pragma unroll
      for (int i = 0; i < 4; ++i) {
        const int o = wm * 64 + mi * 16 + l4 * 4 + i;
        const int n = n0 + wn * 64 + ni * 16 + l15;
        Ht[((size_t)r * DIM + o) * N_NODES + n] = (short)f2bf(acc[mi][ni][i]);
      }
}

// ---------------------------------------------------------------------------
// Kernel 2: main. Block = (relation r, 32 out rows). Grid 1024 = 4 blocks/CU,
// relation == XCD (Ht[r] 1MB L2-resident). Per phase (BK=256):
//   - issue H frags ks=0..3 (L2), then 8x 1KB-contiguous A row loads (HBM)
//   - compute 8 ks-steps from LDS-A(bf16,swizzled) x reg-H, rolling H prefetch
//   - cvt staged A -> bf16, accumulate rowsum, ds_write next buffer, barrier
// Wave w owns o in [w*32, w*32+32) and stages rows w*8..w*8+7.
// ---------------------------------------------------------------------------
__global__ __launch_bounds__(256, 2) void rgcn_main(const float* __restrict__ A,
                                                    const short* __restrict__ Ht,
                                                    float* __restrict__ out) {
  const int bid = blockIdx.x;
  const int logical = (bid & 7) * 128 + (bid >> 3);   // XCD x -> relation x
  const int r  = logical >> 7;
  const int m0 = (logical & 127) * RM;

  const int lane = threadIdx.x & 63;
  const int w    = threadIdx.x >> 6;
  const int l15  = lane & 15, l4 = lane >> 4;

  __shared__ __align__(128) short Ab[2][RM * 256];   // bf16, 512B row stride, XOR swz
  __shared__ float norm_s[RM];

  const float* Ag = A + ((size_t)r * N_NODES + m0 + w * 8) * N_NODES;        // wave's 8 rows
  const short* Hg = Ht + ((size_t)r * DIM + w * 32 + l15) * N_NODES + l4 * 8;

  f32x4 acc[2][2] = {};     // [mt][ot] : 32m x 32o per wave
  f32x4 sg[8];              // staged A (one row-chunk per j)
  float rs[8] = {};         // rowsum partials, row = w*8 + j
  bf16x8 hf[4][2];          // rolling H window [slot][ot]

  auto loadH = [&](int slot, int ks, int kb) {
    hf[slot][0] = *reinterpret_cast<const bf16x8*>(Hg + kb + ks * 32);
    hf[slot][1] = *reinterpret_cast<const bf16x8*>(Hg + (size_t)16 * N_NODES + kb + ks * 32);
  };
  auto stageA = [&](int kb) {
#pragma unroll
    for (int j = 0; j < 8; ++j)
      sg[j] = *reinterpret_cast<const f32x4*>(Ag + (size_t)j * N_NODES + kb + lane * 4);
  };
  auto writeA = [&](char* bufW) {
#pragma unroll
    for (int j = 0; j < 8; ++j) {
      s16x4 v;
#pragma unroll
      for (int i = 0; i < 4; ++i) {
        v[i] = (short)f2bf(sg[j][i]);
        rs[j] += sg[j][i];
      }
      *reinterpret_cast<s16x4*>(bufW + (w * 8 + j) * 512 + ((lane * 8) ^ (j << 4))) = v;
    }
  };
  const int rswz = (l15 & 7) << 4;
  auto readA = [&](const char* bufR, int mt, int ks) {
    return *reinterpret_cast<const bf16x8*>(
        bufR + (mt * 16 + l15) * 512 + ((ks * 64 + l4 * 16) ^ rswz));
  };

  auto phase = [&](char* bufR, char* bufW, int kb, bool pf) {
    loadH(0, 0, kb); loadH(1, 1, kb); loadH(2, 2, kb); loadH(3, 3, kb);
    if (pf) stageA(kb + BK);          // HBM prefetch AFTER H issues (in-order vmcnt)
#pragma unroll
    for (int ks = 0; ks < 8; ++ks) {
      bf16x8 a0 = readA(bufR, 0, ks);
      bf16x8 a1 = readA(bufR, 1, ks);
      acc[0][0] = __builtin_amdgcn_mfma_f32_16x16x32_bf16(a0, hf[ks & 3][0], acc[0][0], 0, 0, 0);
      acc[0][1] = __builtin_amdgcn_mfma_f32_16x16x32_bf16(a0, hf[ks & 3][1], acc[0][1], 0, 0, 0);
      acc[1][0] = __builtin_amdgcn_mfma_f32_16x16x32_bf16(a1, hf[ks & 3][0], acc[1][0], 0, 0, 0);
      acc[1][1] = __builtin_amdgcn_mfma_f32_16x16x32_bf16(a1, hf[ks & 3][1], acc[1][1], 0, 0, 0);
      if (ks < 4) loadH(ks, ks + 4, kb);
    }
    if (pf) writeA(bufW);
    __syncthreads();
  };

  char* b0 = (char*)&Ab[0][0];
  char* b1 = (char*)&Ab[1][0];

  // prologue: stage + write phase-0 tile
  stageA(0);
  writeA(b0);
  __syncthreads();

#pragma unroll 1
  for (int p = 0; p < NKT; p += 2) {
    phase(b0, b1, p * BK, p + 1 < NKT);
    phase(b1, b0, (p + 1) * BK, p + 2 < NKT);
  }

  // rowsum -> norms
#pragma unroll
  for (int j = 0; j < 8; ++j) {
    float s = rs[j];
    s += __shfl_xor(s, 1);  s += __shfl_xor(s, 2);  s += __shfl_xor(s, 4);
    s += __shfl_xor(s, 8);  s += __shfl_xor(s, 16); s += __shfl_xor(s, 32);
    if (lane == 0) norm_s[w * 8 + j] = s + EPS_F;
  }
  __syncthreads();

  float ninv[8];
#pragma unroll
  for (int mt = 0; mt < 2; ++mt)
#pragma unroll
    for (int i = 0; i < 4; ++i)
      ninv[mt * 4 + i] = 1.0f / norm_s[mt * 16 + l4 * 4 + i];

#pragma unroll
  for (int mt = 0; mt < 2; ++mt)
#pragma unroll
    for (int ot = 0; ot < 2; ++ot)
#pragma unroll
      for (int i = 0; i < 4; ++i)
        atomicAdd(&out[(size_t)(m0 + mt * 16 + l4 * 4 + i) * DIM + w * 32 + ot * 16 + l15],
                  acc[mt][ot][i] * ninv[mt * 4 + i]);
}

extern "C" void kernel_launch(void* const* d_in, const int* in_sizes, int n_in,
                              void* d_out, int out_size, void* d_ws, size_t ws_size,
                              hipStream_t stream) {
  const float* X = (const float*)d_in[0];
  const float* A = (const float*)d_in[1];
  const float* W = (const float*)d_in[2];
  float* out = (float*)d_out;
  short* Ht = (short*)d_ws;   // 8 * 128 * 4096 bf16 = 8 MB

  hipMemsetAsync(d_out, 0, (size_t)out_size * sizeof(float), stream);
  hipLaunchKernelGGL(h_kernel, dim3(NREL * (N_NODES / 128)), dim3(256), 0, stream, X, W, Ht);
  hipLaunchKernelGGL(rgcn_main, dim3(NREL * (N_NODES / RM)), dim3(256), 0, stream, A, Ht, out);
}

// Round 7
// 169.310 us; speedup vs baseline: 1.1835x; 1.1835x over previous
//
#include <hip/hip_runtime.h>

// RGCNDirectional: out = sum_r (A[r] @ (X @ W[r]^T)) / (rowsum(A[r]) + eps)
// X:[4096,128] f32, A:[8,4096,4096] f32 (512MB), W:[8,128,128] f32.
// Round 7: ingest-volume reduction. Empirical law across R1-R6: time =
// (VMEM ingest bytes)/7.6 TB/s. BM 64->128 halves H ingest (1MB per block,
// 256 blocks instead of 512): 1.05GB -> 792MB. Structure otherwise = R3/R5:
// swizzled tile Ht2 + global_load_lds, reg-dbuf A, 4-buffer D=2 ring,
// one barrier/phase, steady vmcnt(12).

#define N_NODES 4096
#define DIM     128
#define NREL    8
#define EPS_F   1e-12f
#define BM      128
#define BK      64
#define NKT     (N_NODES / BK)   // 64
#define TILE_SHORTS (DIM * BK)   // 8192 shorts = 16 KB per H tile

typedef __attribute__((ext_vector_type(4))) float f32x4;
typedef __attribute__((ext_vector_type(8))) short bf16x8;

__device__ __forceinline__ unsigned short f2bf(float f) {
  unsigned u = __float_as_uint(f);
  return (unsigned short)((u + 0x7fffu + ((u >> 16) & 1u)) >> 16);   // RNE
}

__device__ __forceinline__ bf16x8 cvt8(const float* p) {
  f32x4 lo = *reinterpret_cast<const f32x4*>(p);
  f32x4 hi = *reinterpret_cast<const f32x4*>(p + 4);
  bf16x8 o;
#pragma unroll
  for (int j = 0; j < 4; ++j) { o[j] = (short)f2bf(lo[j]); o[j + 4] = (short)f2bf(hi[j]); }
  return o;
}

__device__ __forceinline__ void gload_lds16(const void* g, void* l) {
  __builtin_amdgcn_global_load_lds((const __attribute__((address_space(1))) void*)g,
                                   (__attribute__((address_space(3))) void*)l, 16, 0, 0);
}

// ---------------------------------------------------------------------------
// Kernel 1: Ht2[r][kt][ o*64 + (c ^ ((o&7)<<3)) ] = bf16( sum_d X[n][d]*W[r][o][d] )
// n = kt*64 + c. Tile-contiguous + XOR-swizzled: main kernel's global_load_lds
// stays linear and its ds_read_b128 is conflict-free.
// ---------------------------------------------------------------------------
__global__ __launch_bounds__(256) void h_kernel(const float* __restrict__ X,
                                                const float* __restrict__ W,
                                                short* __restrict__ Ht2) {
  const int r  = blockIdx.x >> 5;          // 32 n-tiles of 128
  const int n0 = (blockIdx.x & 31) * 128;
  const int lane = threadIdx.x & 63;
  const int wid  = threadIdx.x >> 6;
  const int wm = wid >> 1, wn = wid & 1;   // 2x2 wave grid, 64x64 per wave
  const int l15 = lane & 15, l4 = lane >> 4;

  const float* Wr = W + (size_t)r * DIM * DIM;
  f32x4 acc[4][4] = {};

#pragma unroll
  for (int ks = 0; ks < 4; ++ks) {         // K = 128 = 4 * 32
    const int k = ks * 32 + l4 * 8;
    bf16x8 a[4], b[4];
#pragma unroll
    for (int mi = 0; mi < 4; ++mi)
      a[mi] = cvt8(Wr + (size_t)(wm * 64 + mi * 16 + l15) * DIM + k);
#pragma unroll
    for (int ni = 0; ni < 4; ++ni)
      b[ni] = cvt8(X + (size_t)(n0 + wn * 64 + ni * 16 + l15) * DIM + k);
#pragma unroll
    for (int mi = 0; mi < 4; ++mi)
#pragma unroll
      for (int ni = 0; ni < 4; ++ni)
        acc[mi][ni] = __builtin_amdgcn_mfma_f32_16x16x32_bf16(a[mi], b[ni], acc[mi][ni], 0, 0, 0);
  }

#pragma unroll
  for (int mi = 0; mi < 4; ++mi)
#pragma unroll
    for (int ni = 0; ni < 4; ++ni)
#pragma unroll
      for (int i = 0; i < 4; ++i) {
        const int o = wm * 64 + mi * 16 + l4 * 4 + i;
        const int n = n0 + wn * 64 + ni * 16 + l15;
        const int kt = n >> 6, c = n & 63;
        Ht2[(size_t)(r * NKT + kt) * TILE_SHORTS + o * 64 + (c ^ ((o & 7) << 3))] =
            (short)f2bf(acc[mi][ni][i]);
      }
}

// ---------------------------------------------------------------------------
// Kernel 2: main. Block = (relation r, 128 out rows), 512 threads, 8 waves
// each owning 16 rows. Grid 256 = 1 block/CU, relation == XCD. Per phase:
// 2x global_load_lds (H tile, split across 8 waves) + 4x A dwordx4 to regs,
// vmcnt(12) + one barrier, 16 MFMA/wave from swizzled LDS H x reg A.
// ---------------------------------------------------------------------------
__global__ __launch_bounds__(512, 2) void rgcn_main(const float* __restrict__ A,
                                                    const short* __restrict__ Ht2,
                                                    float* __restrict__ out) {
  const int logical = (blockIdx.x & 7) * 32 + (blockIdx.x >> 3);   // XCD x -> rel x
  const int r  = logical >> 5;
  const int m0 = (logical & 31) * BM;

  const int tid  = threadIdx.x;
  const int lane = tid & 63;
  const int w    = tid >> 6;             // 0..7, owns rows m0+w*16..+16
  const int l15  = lane & 15, l4 = lane >> 4;

  __shared__ __align__(128) short Hs[4][TILE_SHORTS];   // 64 KB

  const float* Arow = A + ((size_t)r * N_NODES + m0 + w * 16 + l15) * N_NODES + l4 * 8;
  const short* Hgw  = Ht2 + (size_t)r * NKT * TILE_SHORTS + w * 512 + lane * 8;
  short* lds0 = &Hs[0][0] + w * 512;     // wave-uniform staging bases
  short* lds1 = &Hs[1][0] + w * 512;
  short* lds2 = &Hs[2][0] + w * 512;
  short* lds3 = &Hs[3][0] + w * 512;

  f32x4 acc[8] = {};
  f32x4 a0[2][2], a1[2][2], a2[2][2], a3[2][2];
  float rs = 0.f;

  auto stage = [&](short* ldsb, int kt) {
    const short* g = Hgw + (size_t)kt * TILE_SHORTS;
    gload_lds16(g, ldsb);
    gload_lds16(g + 4096, ldsb + 4096);
  };
  auto loadA = [&](f32x4 (&d)[2][2], int kt) {
    const float* p = Arow + kt * BK;
    d[0][0] = *reinterpret_cast<const f32x4*>(p);
    d[0][1] = *reinterpret_cast<const f32x4*>(p + 4);
    d[1][0] = *reinterpret_cast<const f32x4*>(p + 32);
    d[1][1] = *reinterpret_cast<const f32x4*>(p + 36);
  };

  const char* hbase = (const char*)&Hs[0][0] + (size_t)l15 * 128;
  const int swz = (l15 & 7) << 4;
  auto compute = [&](int buf, f32x4 (&av)[2][2]) {
    const char* hb = hbase + (size_t)buf * (TILE_SHORTS * 2);
#pragma unroll
    for (int ks = 0; ks < 2; ++ks) {
      bf16x8 ab;
#pragma unroll
      for (int j = 0; j < 4; ++j) {
        ab[j]     = (short)f2bf(av[ks][0][j]);
        ab[j + 4] = (short)f2bf(av[ks][1][j]);
        rs += av[ks][0][j] + av[ks][1][j];
      }
      const int cb = ks * 64 + l4 * 16;
#pragma unroll
      for (int ni = 0; ni < 8; ++ni) {
        bf16x8 h = *reinterpret_cast<const bf16x8*>(hb + ni * 2048 + (cb ^ swz));
        acc[ni] = __builtin_amdgcn_mfma_f32_16x16x32_bf16(ab, h, acc[ni], 0, 0, 0);
      }
    }
  };

#define VMW(N) do { __builtin_amdgcn_sched_barrier(0);                      \
    asm volatile("s_waitcnt vmcnt(" #N ")" ::: "memory");                   \
    __builtin_amdgcn_sched_barrier(0); } while (0)

  // phase p: issue tile p+2 into buf (p+2)&3, wait tile p landed (12 = two
  // phases' 6 VMEM ops in flight), barrier, compute tile p from buf p&3.
#define PH(C, P, KT) do {                                                   \
    stage(lds##P, KT); loadA(a##P, KT);                                     \
    VMW(12);                                                                \
    __builtin_amdgcn_s_barrier();                                           \
    compute(C, a##C); } while (0)

  // prologue: tiles 0,1 in flight
  stage(lds0, 0); loadA(a0, 0);
  stage(lds1, 1); loadA(a1, 1);

  for (int t = 0; t < NKT - 4; t += 4) {   // phases 0..59
    PH(0, 2, t + 2);
    PH(1, 3, t + 3);
    PH(2, 0, t + 4);
    PH(3, 1, t + 5);
  }
  PH(0, 2, 62);                            // phase 60
  PH(1, 3, 63);                            // phase 61
  VMW(6); __builtin_amdgcn_s_barrier(); compute(2, a2);   // phase 62
  VMW(0); __builtin_amdgcn_s_barrier(); compute(3, a3);   // phase 63

#undef PH
#undef VMW

  // rowsum reduce: lanes {l15, l15+16, l15+32, l15+48} hold partials of row l15
  rs += __shfl_xor(rs, 16);
  rs += __shfl_xor(rs, 32);
  float ninv[4];
#pragma unroll
  for (int i = 0; i < 4; ++i)
    ninv[i] = 1.0f / (__shfl(rs, l4 * 4 + i) + EPS_F);  // source lane's l15 == row

  float* orow = out + (size_t)(m0 + w * 16) * DIM;
#pragma unroll
  for (int ni = 0; ni < 8; ++ni)
#pragma unroll
    for (int i = 0; i < 4; ++i)
      atomicAdd(&orow[(size_t)(l4 * 4 + i) * DIM + ni * 16 + l15], acc[ni][i] * ninv[i]);
}

extern "C" void kernel_launch(void* const* d_in, const int* in_sizes, int n_in,
                              void* d_out, int out_size, void* d_ws, size_t ws_size,
                              hipStream_t stream) {
  const float* X = (const float*)d_in[0];
  const float* A = (const float*)d_in[1];
  const float* W = (const float*)d_in[2];
  float* out = (float*)d_out;
  short* Ht2 = (short*)d_ws;   // 8 r * 64 kt * 16 KB = 8 MB

  hipMemsetAsync(d_out, 0, (size_t)out_size * sizeof(float), stream);
  hipLaunchKernelGGL(h_kernel, dim3(NREL * (N_NODES / 128)), dim3(256), 0, stream, X, W, Ht2);
  hipLaunchKernelGGL(rgcn_main, dim3(NREL * (N_NODES / BM)), dim3(512), 0, stream, A, Ht2, out);
}